// Round 1
// 659.888 us; speedup vs baseline: 1.0245x; 1.0245x over previous
//
#include <hip/hip_runtime.h>
#include <stdint.h>

// FP8 E4M3 bit-exact multiply to FP32 bits.
// Inputs: A,B = [N,8] float32 of 0/1 (bits [S,E3..E0,M2..M0]).
// Output: [N,32] float32 of 0/1 (bits [S,E7..E0,M22..M0]).
// HBM floor: 268 MB read + 537 MB write => ~130 us at 6.3 TB/s.
//
// R1 change vs previous version: the old loads used lane-stride 32 B with
// 16 B payload (a0 = A+2*le, a1 = A+2*le+1), so every load instruction
// carried only 50% of its touched span; with the `nt` hint defeating
// L1/L2 line merging this amplified the read stream ~2x. Now each wave
// loads each 64-element tile as two CONTIGUOUS 1 KiB dwordx4 instructions
// and a shfl_xor(1) pair-exchange hands each lane a full element:
//   even lane l owns local elem l/2      (load0 chunks l, l+1)
//   odd  lane l owns local elem 32+(l>>1) (load1 chunks 64+l-1, 64+l)
// The output wave-transpose just remaps its shfl source through
// owner(s) = ((s&31)<<1) | (s>>5). Stores were already contiguous
// 1 KiB per instruction and are unchanged.
//
// NOTE: __builtin_nontemporal_* requires a NATIVE vector type, not HIP's
// HIP_vector_type struct -- hence nfloat4 (same size/alignment/layout).

typedef float nfloat4 __attribute__((ext_vector_type(4)));

__device__ __forceinline__ uint32_t bit_of(float f) {
    // f is exactly 0.0f (0x00000000) or 1.0f (0x3f800000); bit 23 selects.
    return (__float_as_uint(f) >> 23) & 1u;
}

__device__ __forceinline__ nfloat4 swap_xor1(nfloat4 v) {
    // lane l <-> lane l^1 (stays within the 32-lane half; all lanes active)
    nfloat4 r;
    r.x = __shfl_xor(v.x, 1, 64);
    r.y = __shfl_xor(v.y, 1, 64);
    r.z = __shfl_xor(v.z, 1, 64);
    r.w = __shfl_xor(v.w, 1, 64);
    return r;
}

__device__ __forceinline__ void decode8(const nfloat4 v0, const nfloat4 v1,
                                        uint32_t& s, int& frac, int& exp, int& nz) {
    s = bit_of(v0.x);
    int e = (int)((bit_of(v0.y) << 3) | (bit_of(v0.z) << 2) |
                  (bit_of(v0.w) << 1) |  bit_of(v1.x));
    int m = (int)((bit_of(v1.y) << 2) | (bit_of(v1.z) << 1) | bit_of(v1.w));
    // subnormal normalization: leading one at mantissa bit 2/1/0 ->
    // biased exp 120/119/118, significand shifted to the "1.xxx" slot (8..15)
    int frac_sub = (m >= 4) ? (m << 1) : ((m >= 2) ? (m << 2) : (m << 3));
    int exp_sub  = (m >= 4) ? 120      : ((m >= 2) ? 119      : 118);
    bool normal = (e > 0);
    frac = normal ? (m | 8)   : frac_sub;   // 4-bit significand, leading 1 at bit 3
    exp  = normal ? (e + 120) : exp_sub;    // biased FP32 exponent
    nz   = ((e | m) != 0) ? 1 : 0;
}

__device__ __forceinline__ uint32_t mul_bits(const nfloat4 a0, const nfloat4 a1,
                                             const nfloat4 b0, const nfloat4 b1) {
    uint32_t sa, sb; int fa, ea, fb, eb, nza, nzb;
    decode8(a0, a1, sa, fa, ea, nza);
    decode8(b0, b1, sb, fb, eb, nzb);
    uint32_t sign = sa ^ sb;
    int p = fa * fb;                        // 8-bit product in [64, 225] when nz
    int carry = p >> 7;                     // leading one at bit 7 vs bit 6
    int exp_out = ea + eb - 127 + carry;
    // carry: (p-128)<<16 ; no carry: (p-64)<<17 == (p << (17-carry)) & 0x7fffff
    uint32_t mant = ((uint32_t)p << (17 - carry)) & 0x7fffffu;
    uint32_t bits = (sign << 31) | ((uint32_t)exp_out << 23) | mant;
    if (!(nza & nzb)) bits = sign << 31;    // true zero: keep sign, zero exp/mant
    return bits;
}

// Grid covers n_elem/2; each wave handles 128 consecutive elements as two
// 64-element tiles. Per tile per operand: two contiguous 1 KiB loads +
// one pair-exchange; per tile: wave transpose + eight contiguous 1 KiB stores.
__global__ __launch_bounds__(256) void spike_fp8_mul_kernel(
        const nfloat4* __restrict__ A, const nfloat4* __restrict__ B,
        nfloat4* __restrict__ out, int n_elem) {
    int tid  = blockIdx.x * blockDim.x + threadIdx.x;
    int lane = threadIdx.x & 63;
    int wbase = (tid - lane) * 2;           // first element of this wave's 128
    bool odd = (lane & 1) != 0;

    long long chunk_lim = (long long)n_elem * 2 - 1;  // last valid float4 in A/B

    uint32_t bits[2];
    #pragma unroll
    for (int k = 0; k < 2; ++k) {
        long long cbase = (long long)(wbase + 64 * k) * 2;  // tile chunk base
        long long c0 = cbase + lane;        // contiguous 1 KiB across the wave
        long long c1 = cbase + 64 + lane;   // next contiguous 1 KiB
        if (c0 > chunk_lim) c0 = chunk_lim; // clamp, keep full wave uniform
        if (c1 > chunk_lim) c1 = chunk_lim;
        nfloat4 aL0 = __builtin_nontemporal_load(A + c0);
        nfloat4 aL1 = __builtin_nontemporal_load(A + c1);
        nfloat4 bL0 = __builtin_nontemporal_load(B + c0);
        nfloat4 bL1 = __builtin_nontemporal_load(B + c1);
        nfloat4 aS0 = swap_xor1(aL0);
        nfloat4 aS1 = swap_xor1(aL1);
        nfloat4 bS0 = swap_xor1(bL0);
        nfloat4 bS1 = swap_xor1(bL1);
        // even lane: elem l/2       -> halves (own L0, partner L0)
        // odd  lane: elem 32+(l>>1) -> halves (partner L1, own L1)
        nfloat4 a0 = odd ? aS1 : aL0;
        nfloat4 a1 = odd ? aL1 : aS0;
        nfloat4 b0 = odd ? bS1 : bL0;
        nfloat4 b1 = odd ? bL1 : bS0;
        bits[k] = mul_bits(a0, a1, b0, b1);
    }

    // ---- wave transpose per 64-element tile: lane stores output float4
    // (i*64 + lane); source element within tile s = i*8 + (lane>>3), held by
    // lane owner(s) = ((s&31)<<1)|(s>>5); bit group g = lane&7. ----
    int g   = lane & 7;
    uint32_t m0 = 1u << (31 - (g << 2));
    uint32_t m1 = m0 >> 1, m2 = m0 >> 2, m3 = m0 >> 3;
    long long lim = (long long)n_elem * 8;  // output float4 count

    #pragma unroll
    for (int k = 0; k < 2; ++k) {
        nfloat4* wout = out + (size_t)(wbase + k * 64) * 8;
        #pragma unroll
        for (int i = 0; i < 8; ++i) {
            int s = i * 8 + (lane >> 3);                 // local source element
            int owner = ((s & 31) << 1) | (s >> 5);      // lane that owns it
            uint32_t ub = (uint32_t)__shfl((int)bits[k], owner, 64);
            nfloat4 o;
            o.x = (ub & m0) ? 1.0f : 0.0f;
            o.y = (ub & m1) ? 1.0f : 0.0f;
            o.z = (ub & m2) ? 1.0f : 0.0f;
            o.w = (ub & m3) ? 1.0f : 0.0f;
            long long j = (long long)(wbase + k * 64) * 8 + i * 64 + lane;
            if (j < lim)
                __builtin_nontemporal_store(o, wout + i * 64 + lane);  // 1 KiB/wave
        }
    }
}

extern "C" void kernel_launch(void* const* d_in, const int* in_sizes, int n_in,
                              void* d_out, int out_size, void* d_ws, size_t ws_size,
                              hipStream_t stream) {
    const nfloat4* A = (const nfloat4*)d_in[0];
    const nfloat4* B = (const nfloat4*)d_in[1];
    nfloat4* out     = (nfloat4*)d_out;
    int n_elem = in_sizes[0] / 8;
    const int block = 256;
    int n_thread = (n_elem + 1) / 2;        // two elements per thread
    int grid = (n_thread + block - 1) / block;
    hipLaunchKernelGGL(spike_fp8_mul_kernel, dim3(grid), dim3(block), 0, stream,
                       A, B, out, n_elem);
}